// Round 1
// baseline (8146.727 us; speedup 1.0000x reference)
//
#include <hip/hip_runtime.h>
#include <cstdint>
#include <cstddef>

#define T_SEQ 1024
#define BATCH 64
#define DIM   256
#define HID   256
#define NG    (4*HID)   // 1024 gate columns, j = g*256 + r, g in {f,i,g~,o}

__device__ __forceinline__ float sigm_f(float x) {
    return 1.0f / (1.0f + __expf(-x));
}
__device__ __forceinline__ float tanh_f(float x) {
    x = fminf(fmaxf(x, -15.0f), 15.0f);   // avoid inf/inf
    float e = __expf(2.0f * x);
    return (e - 1.0f) / (e + 1.0f);
}

// ---------------- phase 0: repack weights (k-major), zero state ---------------
// Wx4[(k*256 + r)*4 + g] = W_g[r][k]          (x part, k<256)
// Wz4[((k>>2)*1024 + j)*4 + (k&3)] = W_g[r][256+k]  (h part)
// bias4[r*4+g] = b_g[r]
__global__ void pack_kernel(const float* __restrict__ Wf, const float* __restrict__ bf,
                            const float* __restrict__ Wi, const float* __restrict__ bi,
                            const float* __restrict__ Wg, const float* __restrict__ bg,
                            const float* __restrict__ Wo, const float* __restrict__ bo,
                            float* __restrict__ wx4, float* __restrict__ wz4,
                            float* __restrict__ bias4,
                            float* __restrict__ hstate, float* __restrict__ cstate) {
    int k = blockIdx.x;          // 0..255
    int j = threadIdx.x;         // 0..1023
    int r = j & 255, g = j >> 8;
    const float* W  = (g == 0) ? Wf : (g == 1) ? Wi : (g == 2) ? Wg : Wo;
    const float* bb = (g == 0) ? bf : (g == 1) ? bi : (g == 2) ? bg : bo;
    wx4[((size_t)k * 256 + r) * 4 + g] = W[(size_t)r * 512 + k];
    wz4[(((size_t)(k >> 2)) * 1024 + j) * 4 + (k & 3)] = W[(size_t)r * 512 + 256 + k];
    if (k == 0) bias4[r * 4 + g] = bb[r];
    if (k < 64 && g == 0) hstate[k * 256 + r] = 0.0f;
    if (k < 64 && g == 1) cstate[k * 256 + r] = 0.0f;
}

// ---------------- phase 1: Xproj[row][j] = x_row . Wx_col_j + bias ------------
// 16 rows x 1024 cols per WG of 256 threads; thread handles r=tid across 4 gates.
__global__ __launch_bounds__(256) void xproj_kernel(
        const float* __restrict__ X, const float* __restrict__ wx4,
        const float* __restrict__ bias4, float* __restrict__ xp) {
    __shared__ __align__(16) float xl[256 * 20];   // [k][row] padded to 20 (16B-aligned rows)
    int tid = threadIdx.x;
    int R0 = blockIdx.x * 16;
    #pragma unroll
    for (int i = 0; i < 16; ++i)
        xl[tid * 20 + i] = X[(size_t)(R0 + i) * DIM + tid];   // transpose into LDS
    __syncthreads();

    float4 bv = ((const float4*)bias4)[tid];
    float acc[16][4];
    #pragma unroll
    for (int i = 0; i < 16; ++i) {
        acc[i][0] = bv.x; acc[i][1] = bv.y; acc[i][2] = bv.z; acc[i][3] = bv.w;
    }
    const float4* __restrict__ wp = (const float4*)wx4 + tid;
    #pragma unroll 2
    for (int k = 0; k < 256; ++k) {
        float4 w  = wp[k << 8];                       // Wx4[k][tid][0..3]
        float4 xa = *(const float4*)&xl[k * 20 + 0];  // broadcast reads (conflict-free)
        float4 xb = *(const float4*)&xl[k * 20 + 4];
        float4 xc = *(const float4*)&xl[k * 20 + 8];
        float4 xd = *(const float4*)&xl[k * 20 + 12];
        float xr[16] = {xa.x, xa.y, xa.z, xa.w, xb.x, xb.y, xb.z, xb.w,
                        xc.x, xc.y, xc.z, xc.w, xd.x, xd.y, xd.z, xd.w};
        #pragma unroll
        for (int i = 0; i < 16; ++i) {
            acc[i][0] = fmaf(xr[i], w.x, acc[i][0]);
            acc[i][1] = fmaf(xr[i], w.y, acc[i][1]);
            acc[i][2] = fmaf(xr[i], w.z, acc[i][2]);
            acc[i][3] = fmaf(xr[i], w.w, acc[i][3]);
        }
    }
    #pragma unroll
    for (int i = 0; i < 16; ++i)
        #pragma unroll
        for (int g = 0; g < 4; ++g)
            xp[(size_t)(R0 + i) * NG + g * HID + tid] = acc[i][g];
}

// ---------------- phase 2: sequential recurrence, 1 WG per batch element -----
__global__ __launch_bounds__(1024) void lstm_step_kernel(
        const float* __restrict__ xp, const float* __restrict__ wz4,
        float* __restrict__ hstate, float* __restrict__ cstate,
        float* __restrict__ out, int t0, int Tc) {
    __shared__ __align__(16) float hl[HID];
    __shared__ float cl[HID];
    __shared__ float gl[NG];
    int b = blockIdx.x, j = threadIdx.x;
    int g = j >> 8;
    if (j < HID) { hl[j] = hstate[b * HID + j]; cl[j] = cstate[b * HID + j]; }
    __syncthreads();
    const float4* __restrict__ wp = (const float4*)wz4 + j;
    for (int tt = 0; tt < Tc; ++tt) {
        float acc = xp[((size_t)tt * BATCH + b) * NG + j];
        float s0 = 0.f, s1 = 0.f, s2 = 0.f, s3 = 0.f;
        #pragma unroll 8
        for (int k4 = 0; k4 < 64; ++k4) {
            float4 w  = wp[(size_t)k4 * 1024];                      // Wz4[k4][j][0..3]
            float4 h4 = *reinterpret_cast<const float4*>(&hl[k4 * 4]); // broadcast
            s0 = fmaf(w.x, h4.x, s0);
            s1 = fmaf(w.y, h4.y, s1);
            s2 = fmaf(w.z, h4.z, s2);
            s3 = fmaf(w.w, h4.w, s3);
        }
        acc += (s0 + s1) + (s2 + s3);
        gl[j] = (g == 2) ? tanh_f(acc) : sigm_f(acc);
        __syncthreads();
        if (j < HID) {
            float f  = gl[j];
            float ii = gl[HID + j];
            float gg = gl[2 * HID + j];
            float o  = gl[3 * HID + j];
            float c  = fmaf(f, cl[j], ii * gg);
            cl[j] = c;
            float h = o * tanh_f(c);
            hl[j] = h;
            out[((size_t)(t0 + tt) * BATCH + b) * HID + j] = h;
        }
        __syncthreads();
    }
    if (j < HID) { hstate[b * HID + j] = hl[j]; cstate[b * HID + j] = cl[j]; }
}

// ---------------- tail: final hx, cx ------------------------------------------
__global__ void tail_kernel(const float* __restrict__ hstate,
                            const float* __restrict__ cstate, float* __restrict__ out) {
    int b = blockIdx.x, r = threadIdx.x;
    size_t base = (size_t)T_SEQ * BATCH * HID;
    out[base + b * HID + r] = hstate[b * HID + r];
    out[base + (size_t)BATCH * HID + b * HID + r] = cstate[b * HID + r];
}

extern "C" void kernel_launch(void* const* d_in, const int* in_sizes, int n_in,
                              void* d_out, int out_size, void* d_ws, size_t ws_size,
                              hipStream_t stream) {
    (void)in_sizes; (void)n_in; (void)out_size;
    const float* X  = (const float*)d_in[0];
    const float* Wf = (const float*)d_in[1];
    const float* bf = (const float*)d_in[2];
    const float* Wi = (const float*)d_in[3];
    const float* bi = (const float*)d_in[4];
    const float* Wg = (const float*)d_in[5];
    const float* bg = (const float*)d_in[6];
    const float* Wo = (const float*)d_in[7];
    const float* bo = (const float*)d_in[8];
    float* out = (float*)d_out;
    char*  ws  = (char*)d_ws;

    float* wx4    = (float*)(ws);                         // 1 MB
    float* wz4    = (float*)(ws + (1 << 20));             // 1 MB
    float* bias4  = (float*)(ws + (2 << 20));             // 4 KB
    float* hstate = (float*)(ws + (2 << 20) + 65536);     // 64 KB
    float* cstate = (float*)(ws + (2 << 20) + 2 * 65536); // 64 KB
    float* xproj  = (float*)(ws + (2 << 20) + 3 * 65536); // Tc*64*1024*4 bytes

    size_t fixed = (size_t)(2 << 20) + 3 * 65536;
    int Tc = 1024;   // chunk of timesteps whose x-projection fits in workspace
    while (Tc > 16 && fixed + (size_t)Tc * BATCH * NG * 4 > ws_size) Tc >>= 1;

    pack_kernel<<<256, 1024, 0, stream>>>(Wf, bf, Wi, bi, Wg, bg, Wo, bo,
                                          wx4, wz4, bias4, hstate, cstate);
    for (int t0 = 0; t0 < T_SEQ; t0 += Tc) {
        xproj_kernel<<<Tc * BATCH / 16, 256, 0, stream>>>(
            X + (size_t)t0 * BATCH * DIM, wx4, bias4, xproj);
        lstm_step_kernel<<<BATCH, 1024, 0, stream>>>(
            xproj, wz4, hstate, cstate, out, t0, Tc);
    }
    tail_kernel<<<BATCH, HID, 0, stream>>>(hstate, cstate, out);
}

// Round 2
// 4672.650 us; speedup vs baseline: 1.7435x; 1.7435x over previous
//
#include <hip/hip_runtime.h>
#include <cstdint>
#include <cstddef>

#define T_SEQ 1024
#define BATCH 64
#define DIM   256
#define HID   256
#define NG    (4*HID)   // 1024 gate columns, j = g*256 + r, g in {f,i,g~,o}

typedef _Float16 h2v __attribute__((ext_vector_type(2)));
union U16 { uint4 u; h2v h[4]; };

__device__ __forceinline__ float sigm_f(float x) {
    return 1.0f / (1.0f + __expf(-x));
}
__device__ __forceinline__ float tanh_f(float x) {
    x = fminf(fmaxf(x, -15.0f), 15.0f);   // avoid inf/inf
    float e = __expf(2.0f * x);
    return (e - 1.0f) / (e + 1.0f);
}

// ---------------- phase 0: repack weights, zero state -------------------------
// Wx4[(k*256 + r)*4 + g] = W_g[r][k]                     (x part, fp32)
// Wzh[((k>>3)*1024 + j)*8 + (k&7)] = fp16(W_g[r][256+k]) (h part, fp16 k-packs of 8)
// bias4[r*4+g] = b_g[r]
__global__ void pack_kernel(const float* __restrict__ Wf, const float* __restrict__ bf,
                            const float* __restrict__ Wi, const float* __restrict__ bi,
                            const float* __restrict__ Wg, const float* __restrict__ bg,
                            const float* __restrict__ Wo, const float* __restrict__ bo,
                            float* __restrict__ wx4, _Float16* __restrict__ wzh,
                            float* __restrict__ bias4,
                            float* __restrict__ hstate, float* __restrict__ cstate) {
    int k = blockIdx.x;          // 0..255
    int j = threadIdx.x;         // 0..1023
    int r = j & 255, g = j >> 8;
    const float* W  = (g == 0) ? Wf : (g == 1) ? Wi : (g == 2) ? Wg : Wo;
    const float* bb = (g == 0) ? bf : (g == 1) ? bi : (g == 2) ? bg : bo;
    wx4[((size_t)k * 256 + r) * 4 + g] = W[(size_t)r * 512 + k];
    wzh[(((size_t)(k >> 3)) * 1024 + j) * 8 + (k & 7)] = (_Float16)W[(size_t)r * 512 + 256 + k];
    if (k == 0) bias4[r * 4 + g] = bb[r];
    if (k < 64 && g == 0) hstate[k * 256 + r] = 0.0f;
    if (k < 64 && g == 1) cstate[k * 256 + r] = 0.0f;
}

// ---------------- phase 1: Xproj[row][j] = x_row . Wx_col_j + bias ------------
__global__ __launch_bounds__(256) void xproj_kernel(
        const float* __restrict__ X, const float* __restrict__ wx4,
        const float* __restrict__ bias4, float* __restrict__ xp) {
    __shared__ __align__(16) float xl[256 * 20];   // [k][row] padded
    int tid = threadIdx.x;
    int R0 = blockIdx.x * 16;
    #pragma unroll
    for (int i = 0; i < 16; ++i)
        xl[tid * 20 + i] = X[(size_t)(R0 + i) * DIM + tid];
    __syncthreads();

    float4 bv = ((const float4*)bias4)[tid];
    float acc[16][4];
    #pragma unroll
    for (int i = 0; i < 16; ++i) {
        acc[i][0] = bv.x; acc[i][1] = bv.y; acc[i][2] = bv.z; acc[i][3] = bv.w;
    }
    const float4* __restrict__ wp = (const float4*)wx4 + tid;
    #pragma unroll 2
    for (int k = 0; k < 256; ++k) {
        float4 w  = wp[k << 8];
        float4 xa = *(const float4*)&xl[k * 20 + 0];
        float4 xb = *(const float4*)&xl[k * 20 + 4];
        float4 xc = *(const float4*)&xl[k * 20 + 8];
        float4 xd = *(const float4*)&xl[k * 20 + 12];
        float xr[16] = {xa.x, xa.y, xa.z, xa.w, xb.x, xb.y, xb.z, xb.w,
                        xc.x, xc.y, xc.z, xc.w, xd.x, xd.y, xd.z, xd.w};
        #pragma unroll
        for (int i = 0; i < 16; ++i) {
            acc[i][0] = fmaf(xr[i], w.x, acc[i][0]);
            acc[i][1] = fmaf(xr[i], w.y, acc[i][1]);
            acc[i][2] = fmaf(xr[i], w.z, acc[i][2]);
            acc[i][3] = fmaf(xr[i], w.w, acc[i][3]);
        }
    }
    #pragma unroll
    for (int i = 0; i < 16; ++i)
        #pragma unroll
        for (int g = 0; g < 4; ++g)
            xp[(size_t)(R0 + i) * NG + g * HID + tid] = acc[i][g];
}

// ---------------- phase 2: sequential recurrence, 1 WG per batch element -----
// fp16 weights + fp16 h, fp32 accumulate via v_dot2_f32_f16.
__global__ __launch_bounds__(1024) void lstm_step_kernel(
        const float* __restrict__ xp, const _Float16* __restrict__ wzh,
        float* __restrict__ hstate, float* __restrict__ cstate,
        float* __restrict__ out, int t0, int Tc) {
    __shared__ __align__(16) _Float16 hl2[HID];   // fp16 h for the matvec
    __shared__ float cl[HID];
    __shared__ float gl[NG];
    int b = blockIdx.x, j = threadIdx.x;
    int g = j >> 8;
    if (j < HID) {
        cl[j]  = cstate[b * HID + j];
        hl2[j] = (_Float16)hstate[b * HID + j];
    }
    __syncthreads();
    const uint4* __restrict__ wp = (const uint4*)wzh + j;  // 8 fp16 per element
    for (int tt = 0; tt < Tc; ++tt) {
        float acc = xp[((size_t)tt * BATCH + b) * NG + j];
        float s0 = 0.f, s1 = 0.f, s2 = 0.f, s3 = 0.f;
        #pragma unroll 8
        for (int k8 = 0; k8 < 32; ++k8) {
            U16 w, h;
            w.u = wp[(size_t)k8 * 1024];                       // Wzh[k8][j][0..7]
            h.u = *reinterpret_cast<const uint4*>(&hl2[k8 * 8]); // broadcast, 8 halfs
            s0 = __builtin_amdgcn_fdot2(w.h[0], h.h[0], s0, false);
            s1 = __builtin_amdgcn_fdot2(w.h[1], h.h[1], s1, false);
            s2 = __builtin_amdgcn_fdot2(w.h[2], h.h[2], s2, false);
            s3 = __builtin_amdgcn_fdot2(w.h[3], h.h[3], s3, false);
        }
        acc += (s0 + s1) + (s2 + s3);
        gl[j] = (g == 2) ? tanh_f(acc) : sigm_f(acc);
        __syncthreads();
        if (j < HID) {
            float f  = gl[j];
            float ii = gl[HID + j];
            float gg = gl[2 * HID + j];
            float o  = gl[3 * HID + j];
            float c  = fmaf(f, cl[j], ii * gg);
            cl[j] = c;
            float h = o * tanh_f(c);
            hl2[j] = (_Float16)h;
            out[((size_t)(t0 + tt) * BATCH + b) * HID + j] = h;
        }
        __syncthreads();
    }
    if (j < HID) {
        hstate[b * HID + j] = (float)hl2[j];
        cstate[b * HID + j] = cl[j];
    }
}

// ---------------- tail: final hx, cx ------------------------------------------
__global__ void tail_kernel(const float* __restrict__ hstate,
                            const float* __restrict__ cstate, float* __restrict__ out) {
    int b = blockIdx.x, r = threadIdx.x;
    size_t base = (size_t)T_SEQ * BATCH * HID;
    out[base + b * HID + r] = hstate[b * HID + r];
    out[base + (size_t)BATCH * HID + b * HID + r] = cstate[b * HID + r];
}

extern "C" void kernel_launch(void* const* d_in, const int* in_sizes, int n_in,
                              void* d_out, int out_size, void* d_ws, size_t ws_size,
                              hipStream_t stream) {
    (void)in_sizes; (void)n_in; (void)out_size;
    const float* X  = (const float*)d_in[0];
    const float* Wf = (const float*)d_in[1];
    const float* bf = (const float*)d_in[2];
    const float* Wi = (const float*)d_in[3];
    const float* bi = (const float*)d_in[4];
    const float* Wg = (const float*)d_in[5];
    const float* bg = (const float*)d_in[6];
    const float* Wo = (const float*)d_in[7];
    const float* bo = (const float*)d_in[8];
    float* out = (float*)d_out;
    char*  ws  = (char*)d_ws;

    float*    wx4    = (float*)(ws);                              // 1 MB
    _Float16* wzh    = (_Float16*)(ws + (1 << 20));               // 512 KB
    float*    bias4  = (float*)(ws + (1 << 20) + (512 << 10));    // 4 KB
    float*    hstate = (float*)(ws + (1 << 20) + (512 << 10) + 65536);
    float*    cstate = (float*)(ws + (1 << 20) + (512 << 10) + 2 * 65536);
    float*    xproj  = (float*)(ws + (1 << 20) + (512 << 10) + 3 * 65536);

    size_t fixed = (size_t)(1 << 20) + (512 << 10) + 3 * 65536;
    int Tc = 1024;
    while (Tc > 16 && fixed + (size_t)Tc * BATCH * NG * 4 > ws_size) Tc >>= 1;

    pack_kernel<<<256, 1024, 0, stream>>>(Wf, bf, Wi, bi, Wg, bg, Wo, bo,
                                          wx4, wzh, bias4, hstate, cstate);
    for (int t0 = 0; t0 < T_SEQ; t0 += Tc) {
        xproj_kernel<<<Tc * BATCH / 16, 256, 0, stream>>>(
            X + (size_t)t0 * BATCH * DIM, wx4, bias4, xproj);
        lstm_step_kernel<<<BATCH, 1024, 0, stream>>>(
            xproj, wzh, hstate, cstate, out, t0, Tc);
    }
    tail_kernel<<<BATCH, HID, 0, stream>>>(hstate, cstate, out);
}